// Round 10
// baseline (1130.588 us; speedup 1.0000x reference)
//
#include <hip/hip_runtime.h>
#include <math.h>

// Problem constants (fixed shapes from setup_inputs)
#define Dn   12
#define Hn   448
#define Wn   224
#define HWn  (Hn*Wn)        // 100352
#define DHWn (Dn*HWn)       // 1204224
#define Cn   10

// Y1T layout is OCTET-BLOCKED per slice (c,d): element (L, h) stored at
//   (L>>3)*3584 + h*8 + (L&7)        (3584 = 448*8; octet = 28 KB contiguous)
// where L is the bit-rev-permuted line index (identity L = d7*32+l32).
// - colfft: one block per octet (8 lines, 2 lines/wave for ILP).
// - rowfft stores / irow loads: per d7, 64-B segments; adjacent-row half-waves
//   complete each 128-B cache line -> no over-fetch.
#define OCT_F2 3584

// Twiddle table (float2 in global):
#define TW_W32   0     // 16:  W32^j
#define TW_W7    16    // 7:   W7^j (kept in table but DFT7 uses literals)
#define TW_W64   23    // 32:  W64^j
#define TW_T224  55    // 224: W224^{d7*l32}  [d7*32+l32]
#define TW_T448  279   // 448: W448^{d7*lane} [d7*64+lane]
#define TW_NT    727

// W7^j = exp(-2*pi*i*j/7), compile-time (folds to literals under full unroll)
__device__ __constant__ const float W7R[7] = {
    1.0f,  0.62348980185873359f, -0.22252093395631445f, -0.90096886790241915f,
    -0.90096886790241915f, -0.22252093395631445f, 0.62348980185873359f };
__device__ __constant__ const float W7I[7] = {
    0.0f, -0.78183148246802980f, -0.97492791218182362f, -0.43388373911755823f,
    0.43388373911755823f,  0.97492791218182362f, 0.78183148246802980f };

// ---------- complex helpers ----------
__device__ __forceinline__ float2 cmul(float2 a, float2 b) {
    return make_float2(fmaf(a.x, b.x, -a.y * b.y), fmaf(a.x, b.y, a.y * b.x));
}
__device__ __forceinline__ float2 cfma(float2 a, float2 b, float2 acc) {
    acc.x = fmaf(a.x, b.x, fmaf(-a.y, b.y, acc.x));
    acc.y = fmaf(a.x, b.y, fmaf(a.y, b.x, acc.y));
    return acc;
}
__device__ __forceinline__ float2 cfma_lit(float2 a, float wr, float wi, float2 acc) {
    acc.x = fmaf(a.x, wr, fmaf(-a.y, wi, acc.x));
    acc.y = fmaf(a.x, wi, fmaf(a.y, wr, acc.y));
    return acc;
}
__device__ __forceinline__ float2 cadd(float2 a, float2 b) { return make_float2(a.x + b.x, a.y + b.y); }
__device__ __forceinline__ float2 csub(float2 a, float2 b) { return make_float2(a.x - b.x, a.y - b.y); }
__host__ __device__ constexpr int brev5(int i) {
    return ((i & 1) << 4) | ((i & 2) << 2) | (i & 4) | ((i & 8) >> 2) | ((i & 16) >> 4);
}

__device__ __forceinline__ float2 shflx2(float2 v, int m) {
    return make_float2(__shfl_xor(v.x, m, 64), __shfl_xor(v.y, m, 64));
}

__device__ __forceinline__ double waveReduce(double v) {
#pragma unroll
    for (int o = 32; o > 0; o >>= 1) v += __shfl_down(v, o, 64);
    return v;
}

// ---------- init kernels ----------
__global__ void k_init_misc(float2* __restrict__ tws, double* __restrict__ S) {
    int t = threadIdx.x;  // 1024 threads
    const double PI2 = 6.283185307179586476925287;
    if (t < 16)              { double s, c; sincos(-(PI2 * t) / 32.0, &s, &c); tws[TW_W32 + t] = make_float2((float)c, (float)s); }
    if (t >= 16 && t < 23)   { int j = t - 16; double s, c; sincos(-(PI2 * j) / 7.0,  &s, &c); tws[TW_W7 + j]  = make_float2((float)c, (float)s); }
    if (t >= 23 && t < 55)   { int j = t - 23; double s, c; sincos(-(PI2 * j) / 64.0, &s, &c); tws[TW_W64 + j] = make_float2((float)c, (float)s); }
    if (t >= 55 && t < 279)  { int j = t - 55;  int d7 = j >> 5, l = j & 31;
                               double s, c; sincos(-(PI2 * (d7 * l)) / 224.0, &s, &c);
                               tws[TW_T224 + j] = make_float2((float)c, (float)s); }
    if (t >= 279 && t < 727) { int j = t - 279; int d7 = j >> 6, l = j & 63;
                               double s, c; sincos(-(PI2 * (d7 * l)) / 448.0, &s, &c);
                               tws[TW_T448 + j] = make_float2((float)c, (float)s); }
    if (t >= 727 && t < 759) S[t - 727] = 0.0;
}

__global__ void k_build_p(const float* __restrict__ z, const float* __restrict__ zf,
                          const float* __restrict__ miu,
                          float2* __restrict__ p, float2* __restrict__ r, float2* __restrict__ b,
                          double* __restrict__ S) {
    float mu = fabsf(miu[0]);
    double acc = 0.0;
    for (int e = blockIdx.x * blockDim.x + threadIdx.x; e < DHWn; e += gridDim.x * blockDim.x) {
        int d = e / HWn, rem = e - d * HWn;
        int h = rem / Wn, w = rem - h * Wn;
        int hs = h + Hn / 2; if (hs >= Hn) hs -= Hn;
        int ws = w + Wn / 2; if (ws >= Wn) ws -= Wn;
        int src = d * HWn + hs * Wn + ws;
        float pr = fmaf(mu, z[src], zf[src]);
        float pi = fmaf(mu, z[DHWn + src], zf[DHWn + src]);
        float2 v = make_float2(pr, pi);
        p[e] = v; r[e] = v; b[e] = make_float2(0.f, 0.f);
        acc += (double)pr * pr + (double)pi * pi;
    }
    acc = waveReduce(acc);
    if ((threadIdx.x & 63) == 0) atomicAdd(&S[0], acc);
}

__global__ void k_build_coil(const float* __restrict__ cr, const float* __restrict__ ci,
                             float2* __restrict__ coil) {
    for (int e = blockIdx.x * blockDim.x + threadIdx.x; e < Cn * HWn; e += gridDim.x * blockDim.x) {
        int c = e / HWn, rem = e - c * HWn;
        int h = rem / Wn, w = rem - h * Wn;
        int hs = h + Hn / 2; if (hs >= Hn) hs -= Hn;
        int ws = w + Wn / 2; if (ws >= Wn) ws -= Wn;
        int src = c * HWn + hs * Wn + ws;
        coil[e] = make_float2(cr[src], ci[src]);
    }
}

// permuted + shifted + scaled mask: maskP[L*448 + h], line L holds true
// frequency column w(L) = 7*brev5(L&31) + (L>>5)
__global__ void k_build_mask(const int* __restrict__ mask, float* __restrict__ maskP) {
    for (int e = blockIdx.x * blockDim.x + threadIdx.x; e < HWn; e += gridDim.x * blockDim.x) {
        int L = e / Hn, h = e - L * Hn;
        int w = 7 * brev5(L & 31) + (L >> 5);
        int hs = h + Hn / 2; if (hs >= Hn) hs -= Hn;
        int ws = w + Wn / 2; if (ws >= Wn) ws -= Wn;
        maskP[e] = (float)mask[hs * Wn + ws] * (1.0f / (float)HWn);
    }
}

// ---------- forward row FFT (224 = 7*32 lane-FFT), coil-mul, direct octet store ----------
// No LDS, no barriers. Per d7: lanes form 64-B segments; adjacent-row half-waves
// complete 128-B lines.
__global__ __launch_bounds__(256) void k_rowfft0(const float2* __restrict__ P,
                                                 const float2* __restrict__ coil,
                                                 float2* __restrict__ Y1T,
                                                 const float2* __restrict__ twg,
                                                 int chunkStart) {
    int tid = threadIdx.x;
    int lane = tid & 63, wv = tid >> 6, hi = lane >> 5, l32 = lane & 31;
    int h0 = blockIdx.x * 8, d = blockIdx.y, cz = blockIdx.z;
    int row = h0 + 2 * wv + hi;
    const float2* w32g = twg + TW_W32;
    const float2* t224 = twg + TW_T224;

    const float2* prow = P + (size_t)d * HWn + (size_t)row * Wn;
    const float2* crow = coil + (size_t)(chunkStart + cz) * HWn + (size_t)row * Wn;

    float2 xb[7];
#pragma unroll
    for (int b = 0; b < 7; ++b) xb[b] = cmul(prow[32 * b + l32], crow[32 * b + l32]);

    // DFT7 (literal twiddles)
    float2 y[7];
#pragma unroll
    for (int d7 = 0; d7 < 7; ++d7) {
        float2 s = xb[0];
#pragma unroll
        for (int b = 1; b < 7; ++b) s = cfma_lit(xb[b], W7R[(b * d7) % 7], W7I[(b * d7) % 7], s);
        y[d7] = s;
    }
    // twiddle W224^{l32*d7} from table
#pragma unroll
    for (int d7 = 1; d7 < 7; ++d7) y[d7] = cmul(y[d7], t224[d7 * 32 + l32]);

    // FFT32 across each half-wave, DIF (sign-trick form: y' = (t + s*y)*weff)
#pragma unroll
    for (int s = 0; s < 5; ++s) {
        int dist = 16 >> s;
        float2 wst = w32g[(l32 & (dist - 1)) << s];
        bool h2 = (l32 & dist) != 0;
        float sg = h2 ? -1.f : 1.f;
        float2 weff = h2 ? wst : make_float2(1.f, 0.f);
#pragma unroll
        for (int d7 = 0; d7 < 7; ++d7) {
            float2 t = shflx2(y[d7], dist);
            float2 u = make_float2(fmaf(sg, y[d7].x, t.x), fmaf(sg, y[d7].y, t.y));
            y[d7] = cmul(u, weff);
        }
    }

    // direct store: line L = d7*32+l32 -> octet (L>>3), slot (L&7)
    float2* ybase = Y1T + ((size_t)cz * Dn + d) * (size_t)HWn;
    int oct0 = l32 >> 3, l8 = l32 & 7;
#pragma unroll
    for (int d7 = 0; d7 < 7; ++d7)
        ybase[(size_t)(4 * d7 + oct0) * OCT_F2 + (size_t)row * 8 + l8] = y[d7];
}

// ---------- column FFT448 + mask + IFFT448 ----------
// 256 threads = 4 waves; one block per octet (8 lines), 2 LINES PER WAVE
// (slots wv, wv+4) -> two independent dep-chains fill VALU issue slots.
// LDS 29 KB -> 5 blocks/CU = 20 waves (62.5%), same occupancy as 1-line/wave
// but double ILP. The octet is 28 KB contiguous: dense float4 staging.
#define CP 452
__global__ __launch_bounds__(256) void k_colfft(float2* __restrict__ Y1T,
                                                const float* __restrict__ maskP,
                                                const float2* __restrict__ twg) {
    __shared__ float2 ls[8][CP];
    int tid = threadIdx.x;               // 0..255
    int lane = tid & 63, wv = tid >> 6;  // 4 waves
    int oct = blockIdx.x;                // 28
    int d = blockIdx.y, cz = blockIdx.z;
    const float2* w64t = twg + TW_W64;
    const float2* t448 = twg + TW_T448;

    float2* base = Y1T + ((size_t)cz * Dn + d) * (size_t)HWn + (size_t)oct * OCT_F2;

    // stage in: 3584 f2 = 1792 f4 (7 per thread), fully contiguous
#pragma unroll
    for (int m = 0; m < 7; ++m) {
        int j4 = tid + m * 256;
        int h = j4 >> 2, q = j4 & 3;     // f4 covers slots 2q, 2q+1 at col h
        float4 v = *(const float4*)&base[(size_t)h * 8 + 2 * q];
        ls[2 * q][h]     = make_float2(v.x, v.y);
        ls[2 * q + 1][h] = make_float2(v.z, v.w);
    }
    __syncthreads();

    // twiddles W448^{lane*d7}, shared by both lines (lane-only dependence)
    float2 tp[7];
#pragma unroll
    for (int d7 = 1; d7 < 7; ++d7) tp[d7] = t448[d7 * 64 + lane];

    float2 y[2][7];
    // forward DFT7 (literal twiddles) + W448 twiddle, per line
#pragma unroll
    for (int ln = 0; ln < 2; ++ln) {
        float2 xb[7];
#pragma unroll
        for (int b = 0; b < 7; ++b) xb[b] = ls[wv + 4 * ln][64 * b + lane];
#pragma unroll
        for (int d7 = 0; d7 < 7; ++d7) {
            float2 s = xb[0];
#pragma unroll
            for (int b = 1; b < 7; ++b) s = cfma_lit(xb[b], W7R[(b * d7) % 7], W7I[(b * d7) % 7], s);
            y[ln][d7] = s;
        }
#pragma unroll
        for (int d7 = 1; d7 < 7; ++d7) y[ln][d7] = cmul(y[ln][d7], tp[d7]);
    }

    // FFT64 across lanes, DIF (sign-trick): y' = (t + s*y) * weff
    // (two lines interleaved -> two independent chains per stage)
#pragma unroll
    for (int s = 0; s < 6; ++s) {
        int dist = 32 >> s;
        float2 wst = w64t[(lane & (dist - 1)) << s];
        bool hi = (lane & dist) != 0;
        float sg = hi ? -1.f : 1.f;
        float2 weff = hi ? wst : make_float2(1.f, 0.f);
#pragma unroll
        for (int ln = 0; ln < 2; ++ln)
#pragma unroll
            for (int d7 = 0; d7 < 7; ++d7) {
                float2 t = shflx2(y[ln][d7], dist);
                float2 u = make_float2(fmaf(sg, y[ln][d7].x, t.x), fmaf(sg, y[ln][d7].y, t.y));
                y[ln][d7] = cmul(u, weff);
            }
    }

    // mask: lane holds H-freq index 7*brev6(lane)+d7
    int rb = (brev5(lane & 31) << 1) | (lane >> 5);
#pragma unroll
    for (int ln = 0; ln < 2; ++ln) {
        int L = oct * 8 + wv + 4 * ln;
        const float* mrow = maskP + (size_t)L * Hn + 7 * rb;
#pragma unroll
        for (int d7 = 0; d7 < 7; ++d7) {
            float m = mrow[d7];
            y[ln][d7].x *= m; y[ln][d7].y *= m;
        }
    }

    // inverse FFT64, DIT (sign-trick): y' = A + c*B, c = +-conj(wst)
#pragma unroll
    for (int s = 0; s < 6; ++s) {
        int dist = 1 << s;
        float2 wst = w64t[(lane & (dist - 1)) << (5 - s)];
        wst.y = -wst.y;
        bool hi = (lane & dist) != 0;
        float2 c = hi ? make_float2(-wst.x, -wst.y) : wst;
#pragma unroll
        for (int ln = 0; ln < 2; ++ln)
#pragma unroll
            for (int d7 = 0; d7 < 7; ++d7) {
                float2 t = shflx2(y[ln][d7], dist);
                float2 B = hi ? y[ln][d7] : t;
                float2 A = hi ? t : y[ln][d7];
                y[ln][d7] = cfma(c, B, A);
            }
    }

    // conj W448 twiddle + inverse DFT7 (literal conj twiddles) + LDS writeback
#pragma unroll
    for (int ln = 0; ln < 2; ++ln) {
#pragma unroll
        for (int d7 = 1; d7 < 7; ++d7) {
            float2 c = make_float2(tp[d7].x, -tp[d7].y);
            y[ln][d7] = cmul(y[ln][d7], c);
        }
#pragma unroll
        for (int b = 0; b < 7; ++b) {
            float2 s = y[ln][0];
#pragma unroll
            for (int d7 = 1; d7 < 7; ++d7)
                s = cfma_lit(y[ln][d7], W7R[(b * d7) % 7], -W7I[(b * d7) % 7], s);
            ls[wv + 4 * ln][64 * b + lane] = s;
        }
    }
    __syncthreads();

    // stage out: mirror of stage in (dense float4 stream)
#pragma unroll
    for (int m = 0; m < 7; ++m) {
        int j4 = tid + m * 256;
        int h = j4 >> 2, q = j4 & 3;
        float2 a = ls[2 * q][h];
        float2 b = ls[2 * q + 1][h];
        *(float4*)&base[(size_t)h * 8 + 2 * q] = make_float4(a.x, a.y, b.x, b.y);
    }
}

// ---------- fused inverse row FFT + conj-coil + coil-sum + q/dot epilogue ----------
// Octet layout: each half-wave loads its 7 DIT-ready line-groups directly into
// registers. NO LDS staging, NO barriers in the coil loop.
// Coil loop split over gridDim.z: z-chunk zid handles ccz coils, accumulating
// into partial Qp[zid]; dots are linear in q so each z-chunk adds its partial.
__global__ __launch_bounds__(256) void k_irow_combine(const float2* __restrict__ Y1T,
                                                      const float2* __restrict__ coil,
                                                      const float2* __restrict__ P,
                                                      float2* __restrict__ Qp,
                                                      const float* __restrict__ miu,
                                                      double* __restrict__ S,
                                                      const float2* __restrict__ twg,
                                                      int ccz, int chunkStart,
                                                      int first, int last, int it) {
    __shared__ double sred[8];
    int tid = threadIdx.x;
    int lane = tid & 63, wv = tid >> 6, hi = lane >> 5, l32 = lane & 31;
    int h0 = blockIdx.x * 8, d = blockIdx.y;
    int zid = blockIdx.z;
    int zbase = zid * ccz;
    float2* Q = Qp + (size_t)zid * DHWn;
    int row = h0 + 2 * wv + hi;
    const float2* w32g = twg + TW_W32;
    const float2* t224 = twg + TW_T224;

    float2 tp[7];
#pragma unroll
    for (int d7 = 1; d7 < 7; ++d7) {
        float2 v = t224[d7 * 32 + l32];
        tp[d7] = make_float2(v.x, -v.y);   // conj (inverse twiddle)
    }

    float2 acc[7];
#pragma unroll
    for (int b = 0; b < 7; ++b) acc[b] = make_float2(0.f, 0.f);

    int oct0 = l32 >> 3, l8 = l32 & 7;
    for (int cz = 0; cz < ccz; ++cz) {
        const float2* ybase = Y1T + ((size_t)(zbase + cz) * Dn + d) * (size_t)HWn;
        const float2* crow = coil + (size_t)(chunkStart + zbase + cz) * HWn + (size_t)row * Wn;

        // DIT-ready register loads: y[d7] = line (d7*32+l32) at this row
        float2 y[7];
#pragma unroll
        for (int d7 = 0; d7 < 7; ++d7)
            y[d7] = ybase[(size_t)(4 * d7 + oct0) * OCT_F2 + (size_t)row * 8 + l8];
        float2 cpre[7];
#pragma unroll
        for (int b = 0; b < 7; ++b) cpre[b] = crow[32 * b + l32];

        // inverse FFT32 across half-wave, DIT (sign-trick): y' = A + c*B
#pragma unroll
        for (int s = 0; s < 5; ++s) {
            int dist = 1 << s;
            float2 wst = w32g[(l32 & (dist - 1)) << (4 - s)];
            wst.y = -wst.y;
            bool h2 = (l32 & dist) != 0;
            float2 c = h2 ? make_float2(-wst.x, -wst.y) : wst;
#pragma unroll
            for (int d7 = 0; d7 < 7; ++d7) {
                float2 t = shflx2(y[d7], dist);
                float2 B = h2 ? y[d7] : t;
                float2 A = h2 ? t : y[d7];
                y[d7] = cfma(c, B, A);
            }
        }
        // conj twiddle W224^{-l32*d7}
#pragma unroll
        for (int d7 = 1; d7 < 7; ++d7) y[d7] = cmul(y[d7], tp[d7]);
        // inverse DFT7 (literal conj twiddles) + conj-coil accumulate
#pragma unroll
        for (int b = 0; b < 7; ++b) {
            float2 s = y[0];
#pragma unroll
            for (int d7 = 1; d7 < 7; ++d7)
                s = cfma_lit(y[d7], W7R[(b * d7) % 7], -W7I[(b * d7) % 7], s);
            float2 c = cpre[b];
            acc[b].x += fmaf(s.x, c.x, s.y * c.y);
            acc[b].y += fmaf(s.y, c.x, -s.x * c.y);
        }
    }

    // epilogue: partial q; only zid==0 folds in mu*p (exactly once in the sum).
    float mu = fabsf(miu[0]);
    const float2* prow = P + (size_t)d * HWn + (size_t)row * Wn;
    float2* qrow = Q + (size_t)d * HWn + (size_t)row * Wn;
    double ar = 0.0, ai = 0.0;
#pragma unroll
    for (int b = 0; b < 7; ++b) {
        float2 pv = prow[32 * b + l32];
        float2 s0;
        if (first) {
            if (zid == 0) s0 = make_float2(fmaf(mu, pv.x, acc[b].x), fmaf(mu, pv.y, acc[b].y));
            else          s0 = acc[b];
        } else {
            float2 qv = qrow[32 * b + l32];
            s0 = cadd(qv, acc[b]);
        }
        qrow[32 * b + l32] = s0;
        if (last) {
            ar += (double)(s0.x * pv.x + s0.y * pv.y);
            ai += (double)(s0.y * pv.x - s0.x * pv.y);
        }
    }
    if (last) {
        ar = waveReduce(ar);
        ai = waveReduce(ai);
        if (lane == 0) { sred[wv] = ar; sred[4 + wv] = ai; }
        __syncthreads();
        if (tid == 0) {
            atomicAdd(&S[8 + it],  sred[0] + sred[1] + sred[2] + sred[3]);
            atomicAdd(&S[16 + it], sred[4] + sred[5] + sred[6] + sred[7]);
        }
    }
}

// ---------- CG scalar updates (float4 = 2 complex per lane) ----------
// q points at nz partial buffers, each N2 float4s; summed inline.
__global__ void k_update_br(const double* __restrict__ Sin, double* __restrict__ S, int it,
                            const float4* __restrict__ p, const float4* __restrict__ q,
                            int nz,
                            float4* __restrict__ b, float4* __restrict__ r) {
    double rr = Sin[it], qr = Sin[8 + it], qi = Sin[16 + it];
    double den = qr * qr + qi * qi;
    float arf = (float)(rr * qr / den);
    float aif = (float)(-rr * qi / den);
    double acc = 0.0;
    const int N2 = DHWn / 2;
    for (int e = blockIdx.x * blockDim.x + threadIdx.x; e < N2; e += gridDim.x * blockDim.x) {
        float4 pv = p[e], bv = b[e], rv = r[e];
        float4 qv = q[e];
        for (int z = 1; z < nz; ++z) {
            float4 t = q[(size_t)z * N2 + e];
            qv.x += t.x; qv.y += t.y; qv.z += t.z; qv.w += t.w;
        }
        bv.x += arf * pv.x - aif * pv.y;  bv.y += arf * pv.y + aif * pv.x;
        bv.z += arf * pv.z - aif * pv.w;  bv.w += arf * pv.w + aif * pv.z;
        b[e] = bv;
        rv.x -= arf * qv.x - aif * qv.y;  rv.y -= arf * qv.y + aif * qv.x;
        rv.z -= arf * qv.z - aif * qv.w;  rv.w -= arf * qv.w + aif * qv.z;
        r[e] = rv;
        acc += (double)rv.x * rv.x + (double)rv.y * rv.y
             + (double)rv.z * rv.z + (double)rv.w * rv.w;
    }
    acc = waveReduce(acc);
    if ((threadIdx.x & 63) == 0) atomicAdd(&S[it + 1], acc);
}

__global__ void k_update_p(const double* __restrict__ S, int it,
                           const float4* __restrict__ r, float4* __restrict__ p) {
    float beta = (float)(S[it + 1] / S[it]);
    const int N2 = DHWn / 2;
    for (int e = blockIdx.x * blockDim.x + threadIdx.x; e < N2; e += gridDim.x * blockDim.x) {
        float4 rv = r[e], pv = p[e];
        p[e] = make_float4(fmaf(beta, pv.x, rv.x), fmaf(beta, pv.y, rv.y),
                           fmaf(beta, pv.z, rv.z), fmaf(beta, pv.w, rv.w));
    }
}

__global__ void k_output(const float2* __restrict__ b, float* __restrict__ out) {
    for (int e = blockIdx.x * blockDim.x + threadIdx.x; e < DHWn; e += gridDim.x * blockDim.x) {
        int d = e / HWn, rem = e - d * HWn;
        int h = rem / Wn, w = rem - h * Wn;
        int hs = h + Hn / 2; if (hs >= Hn) hs -= Hn;
        int ws = w + Wn / 2; if (ws >= Wn) ws -= Wn;
        float2 v = b[d * HWn + hs * Wn + ws];
        out[e] = v.x;
        out[DHWn + e] = v.y;
    }
}

extern "C" void kernel_launch(void* const* d_in, const int* in_sizes, int n_in,
                              void* d_out, int out_size, void* d_ws, size_t ws_size,
                              hipStream_t stream) {
    const float* z      = (const float*)d_in[0];
    const float* zf     = (const float*)d_in[1];
    const float* coil_r = (const float*)d_in[2];
    const float* coil_i = (const float*)d_in[3];
    const int*   maskp  = (const int*)d_in[4];
    const float* miu    = (const float*)d_in[5];
    float* out = (float*)d_out;

    char* w = (char*)d_ws;
    size_t off = 0;
    auto carve = [&](size_t bytes) -> void* {
        void* ptr = w + off;
        off += (bytes + 511) & ~(size_t)511;
        return ptr;
    };
    float2* P     = (float2*)carve((size_t)DHWn * 8);
    float2* R     = (float2*)carve((size_t)DHWn * 8);
    float2* Bv    = (float2*)carve((size_t)DHWn * 8);
    float2* COIL  = (float2*)carve((size_t)Cn * HWn * 8);
    float*  MASKP = (float*)carve((size_t)HWn * 4);
    float2* TWS   = (float2*)carve(TW_NT * 8);
    double* S     = (double*)carve(64 * 8);

    size_t imgSet = (size_t)DHWn * 8;   // one coil-slot (12 slices), 9.63 MB
    // (coils staged per chunk, z-splits of the combine); NZ divides cc.
    int cc = 1, NZ = 1;
    {
        const int cand[6][2] = {{10,2},{10,1},{5,1},{2,1},{1,1},{1,1}};
        for (int i = 0; i < 6; ++i) {
            size_t need = off + (size_t)(cand[i][0] + cand[i][1]) * imgSet;
            if (need <= ws_size) { cc = cand[i][0]; NZ = cand[i][1]; break; }
        }
    }
    float2* Qp  = (float2*)carve((size_t)NZ * imgSet);   // NZ partial-q buffers
    float2* Y1T = (float2*)carve((size_t)cc * imgSet);   // staged slices [c][d][oct][h][l8]
    int nch = Cn / cc;
    int ccz = cc / NZ;

    k_init_misc<<<1, 1024, 0, stream>>>(TWS, S);
    k_build_p<<<1024, 256, 0, stream>>>(z, zf, miu, P, R, Bv, S);
    k_build_coil<<<1024, 256, 0, stream>>>(coil_r, coil_i, COIL);
    k_build_mask<<<512, 256, 0, stream>>>(maskp, MASKP);

    for (int it = 0; it < 5; ++it) {
        for (int ch = 0; ch < nch; ++ch) {
            int cs = ch * cc;
            dim3 gf(Hn / 8, Dn, cc);    // 56 x 12 x cc
            dim3 gc(28, Dn, cc);        // octet x d x cc
            dim3 gi(Hn / 8, Dn, NZ);    // 56 x 12 x NZ, each z does cc/NZ coils
            k_rowfft0<<<gf, 256, 0, stream>>>(P, COIL, Y1T, TWS, cs);
            k_colfft<<<gc, 256, 0, stream>>>(Y1T, MASKP, TWS);
            k_irow_combine<<<gi, 256, 0, stream>>>(Y1T, COIL, P, Qp, miu, S, TWS,
                                                   ccz, cs, ch == 0 ? 1 : 0,
                                                   ch == nch - 1 ? 1 : 0, it);
        }
        k_update_br<<<1024, 256, 0, stream>>>(S, S, it, (const float4*)P, (const float4*)Qp,
                                              NZ, (float4*)Bv, (float4*)R);
        if (it < 4) k_update_p<<<1024, 256, 0, stream>>>(S, it, (const float4*)R, (float4*)P);
    }
    k_output<<<1024, 256, 0, stream>>>(Bv, out);
}

// Round 11
// 1092.068 us; speedup vs baseline: 1.0353x; 1.0353x over previous
//
#include <hip/hip_runtime.h>
#include <math.h>

// Problem constants (fixed shapes from setup_inputs)
#define Dn   12
#define Hn   448
#define Wn   224
#define HWn  (Hn*Wn)        // 100352
#define DHWn (Dn*HWn)       // 1204224
#define Cn   10

// Y1T layout is OCTET-BLOCKED per slice (c,d): element (L, h) stored at
//   (L>>3)*3584 + h*8 + (L&7)        (3584 = 448*8; octet = 28 KB contiguous)
// where L is the bit-rev-permuted line index (identity L = d7*32+l32).
// - colfft: one block per HALF-octet (4 lines); the two halves of an octet are
//   placed 336 bids apart (= 0 mod 8) so they land on the SAME XCD and share L2.
// - rowfft stores / irow loads: per d7, 64-B segments; adjacent-row half-waves
//   complete each 128-B cache line -> no over-fetch.
#define OCT_F2 3584

// Twiddle table (float2 in global):
#define TW_W32   0     // 16:  W32^j
#define TW_W7    16    // 7:   W7^j (unused by Winograd path, kept for layout)
#define TW_W64   23    // 32:  W64^j
#define TW_T224  55    // 224: W224^{d7*l32}  [d7*32+l32]
#define TW_T448  279   // 448: W448^{d7*lane} [d7*64+lane]
#define TW_NT    727

// ---------- complex helpers ----------
__device__ __forceinline__ float2 cmul(float2 a, float2 b) {
    return make_float2(fmaf(a.x, b.x, -a.y * b.y), fmaf(a.x, b.y, a.y * b.x));
}
__device__ __forceinline__ float2 cfma(float2 a, float2 b, float2 acc) {
    acc.x = fmaf(a.x, b.x, fmaf(-a.y, b.y, acc.x));
    acc.y = fmaf(a.x, b.y, fmaf(a.y, b.x, acc.y));
    return acc;
}
__device__ __forceinline__ float2 cadd(float2 a, float2 b) { return make_float2(a.x + b.x, a.y + b.y); }
__device__ __forceinline__ float2 csub(float2 a, float2 b) { return make_float2(a.x - b.x, a.y - b.y); }
__host__ __device__ constexpr int brev5(int i) {
    return ((i & 1) << 4) | ((i & 2) << 2) | (i & 4) | ((i & 8) >> 2) | ((i & 16) >> 4);
}

__device__ __forceinline__ float2 shflx2(float2 v, int m) {
    return make_float2(__shfl_xor(v.x, m, 64), __shfl_xor(v.y, m, 64));
}

__device__ __forceinline__ double waveReduce(double v) {
#pragma unroll
    for (int o = 32; o > 0; o >>= 1) v += __shfl_down(v, o, 64);
    return v;
}

// ---------- Winograd-style DFT-7 (66 VALU ops vs 168 naive) ----------
// Forward (SGN=+1): y[k] = Sum_n x[n] exp(-2*pi*i*n*k/7) = A_k - i*B_k
// Inverse (SGN=-1): conj twiddles -> y[k] = A_k + i*B_k
// Verified component-wise against the naive W7R/W7I formulation.
template<int SGN>
__device__ __forceinline__ void dft7(const float2* __restrict__ x, float2* __restrict__ y) {
    const float c1 =  0.62348980185873359f;   // cos(2pi/7)
    const float c2 = -0.22252093395631445f;   // cos(4pi/7)
    const float c3 = -0.90096886790241915f;   // cos(6pi/7)
    const float s1 =  0.78183148246802980f;   // sin(2pi/7)
    const float s2 =  0.97492791218182362f;   // sin(4pi/7)
    const float s3 =  0.43388373911755823f;   // sin(6pi/7)
    float2 u1 = cadd(x[1], x[6]), v1 = csub(x[1], x[6]);
    float2 u2 = cadd(x[2], x[5]), v2 = csub(x[2], x[5]);
    float2 u3 = cadd(x[3], x[4]), v3 = csub(x[3], x[4]);
    y[0] = make_float2(x[0].x + u1.x + u2.x + u3.x,
                       x[0].y + u1.y + u2.y + u3.y);
    float2 A1, A2, A3, B1, B2, B3;
    A1.x = fmaf(c1, u1.x, fmaf(c2, u2.x, fmaf(c3, u3.x, x[0].x)));
    A1.y = fmaf(c1, u1.y, fmaf(c2, u2.y, fmaf(c3, u3.y, x[0].y)));
    A2.x = fmaf(c2, u1.x, fmaf(c3, u2.x, fmaf(c1, u3.x, x[0].x)));
    A2.y = fmaf(c2, u1.y, fmaf(c3, u2.y, fmaf(c1, u3.y, x[0].y)));
    A3.x = fmaf(c3, u1.x, fmaf(c1, u2.x, fmaf(c2, u3.x, x[0].x)));
    A3.y = fmaf(c3, u1.y, fmaf(c1, u2.y, fmaf(c2, u3.y, x[0].y)));
    B1.x = fmaf(s1, v1.x, fmaf(s2, v2.x,  s3 * v3.x));
    B1.y = fmaf(s1, v1.y, fmaf(s2, v2.y,  s3 * v3.y));
    B2.x = fmaf(s2, v1.x, fmaf(-s3, v2.x, -s1 * v3.x));
    B2.y = fmaf(s2, v1.y, fmaf(-s3, v2.y, -s1 * v3.y));
    B3.x = fmaf(s3, v1.x, fmaf(-s1, v2.x,  s2 * v3.x));
    B3.y = fmaf(s3, v1.y, fmaf(-s1, v2.y,  s2 * v3.y));
    if (SGN > 0) {
        y[1] = make_float2(A1.x + B1.y, A1.y - B1.x);
        y[6] = make_float2(A1.x - B1.y, A1.y + B1.x);
        y[2] = make_float2(A2.x + B2.y, A2.y - B2.x);
        y[5] = make_float2(A2.x - B2.y, A2.y + B2.x);
        y[3] = make_float2(A3.x + B3.y, A3.y - B3.x);
        y[4] = make_float2(A3.x - B3.y, A3.y + B3.x);
    } else {
        y[1] = make_float2(A1.x - B1.y, A1.y + B1.x);
        y[6] = make_float2(A1.x + B1.y, A1.y - B1.x);
        y[2] = make_float2(A2.x - B2.y, A2.y + B2.x);
        y[5] = make_float2(A2.x + B2.y, A2.y - B2.x);
        y[3] = make_float2(A3.x - B3.y, A3.y + B3.x);
        y[4] = make_float2(A3.x + B3.y, A3.y - B3.x);
    }
}

// ---------- init kernels ----------
__global__ void k_init_misc(float2* __restrict__ tws, double* __restrict__ S) {
    int t = threadIdx.x;  // 1024 threads
    const double PI2 = 6.283185307179586476925287;
    if (t < 16)              { double s, c; sincos(-(PI2 * t) / 32.0, &s, &c); tws[TW_W32 + t] = make_float2((float)c, (float)s); }
    if (t >= 16 && t < 23)   { int j = t - 16; double s, c; sincos(-(PI2 * j) / 7.0,  &s, &c); tws[TW_W7 + j]  = make_float2((float)c, (float)s); }
    if (t >= 23 && t < 55)   { int j = t - 23; double s, c; sincos(-(PI2 * j) / 64.0, &s, &c); tws[TW_W64 + j] = make_float2((float)c, (float)s); }
    if (t >= 55 && t < 279)  { int j = t - 55;  int d7 = j >> 5, l = j & 31;
                               double s, c; sincos(-(PI2 * (d7 * l)) / 224.0, &s, &c);
                               tws[TW_T224 + j] = make_float2((float)c, (float)s); }
    if (t >= 279 && t < 727) { int j = t - 279; int d7 = j >> 6, l = j & 63;
                               double s, c; sincos(-(PI2 * (d7 * l)) / 448.0, &s, &c);
                               tws[TW_T448 + j] = make_float2((float)c, (float)s); }
    if (t >= 727 && t < 759) S[t - 727] = 0.0;
}

__global__ void k_build_p(const float* __restrict__ z, const float* __restrict__ zf,
                          const float* __restrict__ miu,
                          float2* __restrict__ p, float2* __restrict__ r, float2* __restrict__ b,
                          double* __restrict__ S) {
    float mu = fabsf(miu[0]);
    double acc = 0.0;
    for (int e = blockIdx.x * blockDim.x + threadIdx.x; e < DHWn; e += gridDim.x * blockDim.x) {
        int d = e / HWn, rem = e - d * HWn;
        int h = rem / Wn, w = rem - h * Wn;
        int hs = h + Hn / 2; if (hs >= Hn) hs -= Hn;
        int ws = w + Wn / 2; if (ws >= Wn) ws -= Wn;
        int src = d * HWn + hs * Wn + ws;
        float pr = fmaf(mu, z[src], zf[src]);
        float pi = fmaf(mu, z[DHWn + src], zf[DHWn + src]);
        float2 v = make_float2(pr, pi);
        p[e] = v; r[e] = v; b[e] = make_float2(0.f, 0.f);
        acc += (double)pr * pr + (double)pi * pi;
    }
    acc = waveReduce(acc);
    if ((threadIdx.x & 63) == 0) atomicAdd(&S[0], acc);
}

__global__ void k_build_coil(const float* __restrict__ cr, const float* __restrict__ ci,
                             float2* __restrict__ coil) {
    for (int e = blockIdx.x * blockDim.x + threadIdx.x; e < Cn * HWn; e += gridDim.x * blockDim.x) {
        int c = e / HWn, rem = e - c * HWn;
        int h = rem / Wn, w = rem - h * Wn;
        int hs = h + Hn / 2; if (hs >= Hn) hs -= Hn;
        int ws = w + Wn / 2; if (ws >= Wn) ws -= Wn;
        int src = c * HWn + hs * Wn + ws;
        coil[e] = make_float2(cr[src], ci[src]);
    }
}

// permuted + shifted + scaled mask: maskP[L*448 + h], line L holds true
// frequency column w(L) = 7*brev5(L&31) + (L>>5)
__global__ void k_build_mask(const int* __restrict__ mask, float* __restrict__ maskP) {
    for (int e = blockIdx.x * blockDim.x + threadIdx.x; e < HWn; e += gridDim.x * blockDim.x) {
        int L = e / Hn, h = e - L * Hn;
        int w = 7 * brev5(L & 31) + (L >> 5);
        int hs = h + Hn / 2; if (hs >= Hn) hs -= Hn;
        int ws = w + Wn / 2; if (ws >= Wn) ws -= Wn;
        maskP[e] = (float)mask[hs * Wn + ws] * (1.0f / (float)HWn);
    }
}

// ---------- forward row FFT (224 = 7*32 lane-FFT), coil-mul, direct octet store ----------
// No LDS, no barriers. Per d7: lanes form 64-B segments; adjacent-row half-waves
// complete 128-B lines.
__global__ __launch_bounds__(256) void k_rowfft0(const float2* __restrict__ P,
                                                 const float2* __restrict__ coil,
                                                 float2* __restrict__ Y1T,
                                                 const float2* __restrict__ twg,
                                                 int chunkStart) {
    int tid = threadIdx.x;
    int lane = tid & 63, wv = tid >> 6, hi = lane >> 5, l32 = lane & 31;
    int h0 = blockIdx.x * 8, d = blockIdx.y, cz = blockIdx.z;
    int row = h0 + 2 * wv + hi;
    const float2* w32g = twg + TW_W32;
    const float2* t224 = twg + TW_T224;

    const float2* prow = P + (size_t)d * HWn + (size_t)row * Wn;
    const float2* crow = coil + (size_t)(chunkStart + cz) * HWn + (size_t)row * Wn;

    float2 xb[7];
#pragma unroll
    for (int b = 0; b < 7; ++b) xb[b] = cmul(prow[32 * b + l32], crow[32 * b + l32]);

    // DFT7 (Winograd)
    float2 y[7];
    dft7<1>(xb, y);
    // twiddle W224^{l32*d7} from table
#pragma unroll
    for (int d7 = 1; d7 < 7; ++d7) y[d7] = cmul(y[d7], t224[d7 * 32 + l32]);

    // FFT32 across each half-wave, DIF (sign-trick form: y' = (t + s*y)*weff)
#pragma unroll
    for (int s = 0; s < 5; ++s) {
        int dist = 16 >> s;
        float2 wst = w32g[(l32 & (dist - 1)) << s];
        bool h2 = (l32 & dist) != 0;
        float sg = h2 ? -1.f : 1.f;
        float2 weff = h2 ? wst : make_float2(1.f, 0.f);
#pragma unroll
        for (int d7 = 0; d7 < 7; ++d7) {
            float2 t = shflx2(y[d7], dist);
            float2 u = make_float2(fmaf(sg, y[d7].x, t.x), fmaf(sg, y[d7].y, t.y));
            y[d7] = cmul(u, weff);
        }
    }

    // direct store: line L = d7*32+l32 -> octet (L>>3), slot (L&7)
    float2* ybase = Y1T + ((size_t)cz * Dn + d) * (size_t)HWn;
    int oct0 = l32 >> 3, l8 = l32 & 7;
#pragma unroll
    for (int d7 = 0; d7 < 7; ++d7)
        ybase[(size_t)(4 * d7 + oct0) * OCT_F2 + (size_t)row * 8 + l8] = y[d7];
}

// ---------- column FFT448 + mask + IFFT448 ----------
// 256 threads = 4 waves; one block per HALF-octet (4 lines, 1 line/wave).
// LDS 14.5 KB -> 8 blocks/CU wave-slot cap. gridDim.y = 24 encodes (d, half);
// sibling halves differ by 28*12=336 bids (multiple of 8) -> same XCD -> L2
// merges the interleaved 32-B reads.
#define CP 452
__global__ __launch_bounds__(256) void k_colfft(float2* __restrict__ Y1T,
                                                const float* __restrict__ maskP,
                                                const float2* __restrict__ twg) {
    __shared__ float2 ls[4][CP];
    int tid = threadIdx.x;               // 0..255
    int lane = tid & 63, wv = tid >> 6;  // 4 waves
    int oct = blockIdx.x;                // 28
    int byy = blockIdx.y;                // 24 = d + 12*half
    int d = (byy < 12) ? byy : byy - 12;
    int half = (byy < 12) ? 0 : 1;
    int cz = blockIdx.z;
    const float2* w64t = twg + TW_W64;
    const float2* t448 = twg + TW_T448;

    float2* base = Y1T + ((size_t)cz * Dn + d) * (size_t)HWn + (size_t)oct * OCT_F2
                 + 4 * half;             // slots 4*half .. 4*half+3

    // stage in: 448 h x 4 slots = 1792 f2 = 896 f4 (two f4 per h)
#pragma unroll
    for (int m = 0; m < 4; ++m) {
        int j4 = tid + m * 256;
        if (j4 < 896) {
            int h = j4 >> 1, q = j4 & 1;     // f4 covers local slots 2q, 2q+1 at col h
            float4 v = *(const float4*)&base[(size_t)h * 8 + 2 * q];
            ls[2 * q][h]     = make_float2(v.x, v.y);
            ls[2 * q + 1][h] = make_float2(v.z, v.w);
        }
    }
    __syncthreads();

    int L = oct * 8 + 4 * half + wv;     // this wave's line

    float2 xb[7];
#pragma unroll
    for (int b = 0; b < 7; ++b) xb[b] = ls[wv][64 * b + lane];

    // twiddles W448^{lane*d7} (reused conjugated in the inverse pass)
    float2 tp[7];
#pragma unroll
    for (int d7 = 1; d7 < 7; ++d7) tp[d7] = t448[d7 * 64 + lane];

    // forward DFT7 (Winograd) + W448 twiddle
    float2 y[7];
    dft7<1>(xb, y);
#pragma unroll
    for (int d7 = 1; d7 < 7; ++d7) y[d7] = cmul(y[d7], tp[d7]);

    // FFT64 across lanes, DIF (sign-trick): y' = (t + s*y) * weff
#pragma unroll
    for (int s = 0; s < 6; ++s) {
        int dist = 32 >> s;
        float2 wst = w64t[(lane & (dist - 1)) << s];
        bool hi = (lane & dist) != 0;
        float sg = hi ? -1.f : 1.f;
        float2 weff = hi ? wst : make_float2(1.f, 0.f);
#pragma unroll
        for (int d7 = 0; d7 < 7; ++d7) {
            float2 t = shflx2(y[d7], dist);
            float2 u = make_float2(fmaf(sg, y[d7].x, t.x), fmaf(sg, y[d7].y, t.y));
            y[d7] = cmul(u, weff);
        }
    }

    // mask: lane holds H-freq index 7*brev6(lane)+d7
    int rb = (brev5(lane & 31) << 1) | (lane >> 5);
    const float* mrow = maskP + (size_t)L * Hn + 7 * rb;
#pragma unroll
    for (int d7 = 0; d7 < 7; ++d7) {
        float m = mrow[d7];
        y[d7].x *= m; y[d7].y *= m;
    }

    // inverse FFT64, DIT (sign-trick): y' = A + c*B, c = +-conj(wst)
#pragma unroll
    for (int s = 0; s < 6; ++s) {
        int dist = 1 << s;
        float2 wst = w64t[(lane & (dist - 1)) << (5 - s)];
        wst.y = -wst.y;
        bool hi = (lane & dist) != 0;
        float2 c = hi ? make_float2(-wst.x, -wst.y) : wst;
#pragma unroll
        for (int d7 = 0; d7 < 7; ++d7) {
            float2 t = shflx2(y[d7], dist);
            float2 B = hi ? y[d7] : t;
            float2 A = hi ? t : y[d7];
            y[d7] = cfma(c, B, A);
        }
    }
    // conj W448 twiddle + inverse DFT7 (Winograd) + LDS writeback
#pragma unroll
    for (int d7 = 1; d7 < 7; ++d7) {
        float2 c = make_float2(tp[d7].x, -tp[d7].y);
        y[d7] = cmul(y[d7], c);
    }
    dft7<-1>(y, xb);
#pragma unroll
    for (int b = 0; b < 7; ++b) ls[wv][64 * b + lane] = xb[b];
    __syncthreads();

    // stage out: mirror of stage in
#pragma unroll
    for (int m = 0; m < 4; ++m) {
        int j4 = tid + m * 256;
        if (j4 < 896) {
            int h = j4 >> 1, q = j4 & 1;
            float2 a = ls[2 * q][h];
            float2 b = ls[2 * q + 1][h];
            *(float4*)&base[(size_t)h * 8 + 2 * q] = make_float4(a.x, a.y, b.x, b.y);
        }
    }
}

// ---------- fused inverse row FFT + conj-coil + coil-sum + q/dot epilogue ----------
// Octet layout: each half-wave loads its 7 DIT-ready line-groups directly into
// registers. NO LDS staging, NO barriers in the coil loop.
// Coil loop split over gridDim.z: z-chunk zid handles ccz coils, accumulating
// into partial Qp[zid]; dots are linear in q so each z-chunk adds its partial.
__global__ __launch_bounds__(256) void k_irow_combine(const float2* __restrict__ Y1T,
                                                      const float2* __restrict__ coil,
                                                      const float2* __restrict__ P,
                                                      float2* __restrict__ Qp,
                                                      const float* __restrict__ miu,
                                                      double* __restrict__ S,
                                                      const float2* __restrict__ twg,
                                                      int ccz, int chunkStart,
                                                      int first, int last, int it) {
    __shared__ double sred[8];
    int tid = threadIdx.x;
    int lane = tid & 63, wv = tid >> 6, hi = lane >> 5, l32 = lane & 31;
    int h0 = blockIdx.x * 8, d = blockIdx.y;
    int zid = blockIdx.z;
    int zbase = zid * ccz;
    float2* Q = Qp + (size_t)zid * DHWn;
    int row = h0 + 2 * wv + hi;
    const float2* w32g = twg + TW_W32;
    const float2* t224 = twg + TW_T224;

    float2 tp[7];
#pragma unroll
    for (int d7 = 1; d7 < 7; ++d7) {
        float2 v = t224[d7 * 32 + l32];
        tp[d7] = make_float2(v.x, -v.y);   // conj (inverse twiddle)
    }

    float2 acc[7];
#pragma unroll
    for (int b = 0; b < 7; ++b) acc[b] = make_float2(0.f, 0.f);

    int oct0 = l32 >> 3, l8 = l32 & 7;
    for (int cz = 0; cz < ccz; ++cz) {
        const float2* ybase = Y1T + ((size_t)(zbase + cz) * Dn + d) * (size_t)HWn;
        const float2* crow = coil + (size_t)(chunkStart + zbase + cz) * HWn + (size_t)row * Wn;

        // DIT-ready register loads: y[d7] = line (d7*32+l32) at this row
        float2 y[7];
#pragma unroll
        for (int d7 = 0; d7 < 7; ++d7)
            y[d7] = ybase[(size_t)(4 * d7 + oct0) * OCT_F2 + (size_t)row * 8 + l8];
        float2 cpre[7];
#pragma unroll
        for (int b = 0; b < 7; ++b) cpre[b] = crow[32 * b + l32];

        // inverse FFT32 across half-wave, DIT (sign-trick): y' = A + c*B
#pragma unroll
        for (int s = 0; s < 5; ++s) {
            int dist = 1 << s;
            float2 wst = w32g[(l32 & (dist - 1)) << (4 - s)];
            wst.y = -wst.y;
            bool h2 = (l32 & dist) != 0;
            float2 c = h2 ? make_float2(-wst.x, -wst.y) : wst;
#pragma unroll
            for (int d7 = 0; d7 < 7; ++d7) {
                float2 t = shflx2(y[d7], dist);
                float2 B = h2 ? y[d7] : t;
                float2 A = h2 ? t : y[d7];
                y[d7] = cfma(c, B, A);
            }
        }
        // conj twiddle W224^{-l32*d7}
#pragma unroll
        for (int d7 = 1; d7 < 7; ++d7) y[d7] = cmul(y[d7], tp[d7]);
        // inverse DFT7 (Winograd) + conj-coil accumulate
        float2 s7[7];
        dft7<-1>(y, s7);
#pragma unroll
        for (int b = 0; b < 7; ++b) {
            float2 s = s7[b];
            float2 c = cpre[b];
            acc[b].x += fmaf(s.x, c.x, s.y * c.y);
            acc[b].y += fmaf(s.y, c.x, -s.x * c.y);
        }
    }

    // epilogue: partial q; only zid==0 folds in mu*p (exactly once in the sum).
    float mu = fabsf(miu[0]);
    const float2* prow = P + (size_t)d * HWn + (size_t)row * Wn;
    float2* qrow = Q + (size_t)d * HWn + (size_t)row * Wn;
    double ar = 0.0, ai = 0.0;
#pragma unroll
    for (int b = 0; b < 7; ++b) {
        float2 pv = prow[32 * b + l32];
        float2 s0;
        if (first) {
            if (zid == 0) s0 = make_float2(fmaf(mu, pv.x, acc[b].x), fmaf(mu, pv.y, acc[b].y));
            else          s0 = acc[b];
        } else {
            float2 qv = qrow[32 * b + l32];
            s0 = cadd(qv, acc[b]);
        }
        qrow[32 * b + l32] = s0;
        if (last) {
            ar += (double)(s0.x * pv.x + s0.y * pv.y);
            ai += (double)(s0.y * pv.x - s0.x * pv.y);
        }
    }
    if (last) {
        ar = waveReduce(ar);
        ai = waveReduce(ai);
        if (lane == 0) { sred[wv] = ar; sred[4 + wv] = ai; }
        __syncthreads();
        if (tid == 0) {
            atomicAdd(&S[8 + it],  sred[0] + sred[1] + sred[2] + sred[3]);
            atomicAdd(&S[16 + it], sred[4] + sred[5] + sred[6] + sred[7]);
        }
    }
}

// ---------- CG scalar updates (float4 = 2 complex per lane) ----------
// q points at nz partial buffers, each N2 float4s; summed inline.
__global__ void k_update_br(const double* __restrict__ Sin, double* __restrict__ S, int it,
                            const float4* __restrict__ p, const float4* __restrict__ q,
                            int nz,
                            float4* __restrict__ b, float4* __restrict__ r) {
    double rr = Sin[it], qr = Sin[8 + it], qi = Sin[16 + it];
    double den = qr * qr + qi * qi;
    float arf = (float)(rr * qr / den);
    float aif = (float)(-rr * qi / den);
    double acc = 0.0;
    const int N2 = DHWn / 2;
    for (int e = blockIdx.x * blockDim.x + threadIdx.x; e < N2; e += gridDim.x * blockDim.x) {
        float4 pv = p[e], bv = b[e], rv = r[e];
        float4 qv = q[e];
        for (int z = 1; z < nz; ++z) {
            float4 t = q[(size_t)z * N2 + e];
            qv.x += t.x; qv.y += t.y; qv.z += t.z; qv.w += t.w;
        }
        bv.x += arf * pv.x - aif * pv.y;  bv.y += arf * pv.y + aif * pv.x;
        bv.z += arf * pv.z - aif * pv.w;  bv.w += arf * pv.w + aif * pv.z;
        b[e] = bv;
        rv.x -= arf * qv.x - aif * qv.y;  rv.y -= arf * qv.y + aif * qv.x;
        rv.z -= arf * qv.z - aif * qv.w;  rv.w -= arf * qv.w + aif * qv.z;
        r[e] = rv;
        acc += (double)rv.x * rv.x + (double)rv.y * rv.y
             + (double)rv.z * rv.z + (double)rv.w * rv.w;
    }
    acc = waveReduce(acc);
    if ((threadIdx.x & 63) == 0) atomicAdd(&S[it + 1], acc);
}

__global__ void k_update_p(const double* __restrict__ S, int it,
                           const float4* __restrict__ r, float4* __restrict__ p) {
    float beta = (float)(S[it + 1] / S[it]);
    const int N2 = DHWn / 2;
    for (int e = blockIdx.x * blockDim.x + threadIdx.x; e < N2; e += gridDim.x * blockDim.x) {
        float4 rv = r[e], pv = p[e];
        p[e] = make_float4(fmaf(beta, pv.x, rv.x), fmaf(beta, pv.y, rv.y),
                           fmaf(beta, pv.z, rv.z), fmaf(beta, pv.w, rv.w));
    }
}

__global__ void k_output(const float2* __restrict__ b, float* __restrict__ out) {
    for (int e = blockIdx.x * blockDim.x + threadIdx.x; e < DHWn; e += gridDim.x * blockDim.x) {
        int d = e / HWn, rem = e - d * HWn;
        int h = rem / Wn, w = rem - h * Wn;
        int hs = h + Hn / 2; if (hs >= Hn) hs -= Hn;
        int ws = w + Wn / 2; if (ws >= Wn) ws -= Wn;
        float2 v = b[d * HWn + hs * Wn + ws];
        out[e] = v.x;
        out[DHWn + e] = v.y;
    }
}

extern "C" void kernel_launch(void* const* d_in, const int* in_sizes, int n_in,
                              void* d_out, int out_size, void* d_ws, size_t ws_size,
                              hipStream_t stream) {
    const float* z      = (const float*)d_in[0];
    const float* zf     = (const float*)d_in[1];
    const float* coil_r = (const float*)d_in[2];
    const float* coil_i = (const float*)d_in[3];
    const int*   maskp  = (const int*)d_in[4];
    const float* miu    = (const float*)d_in[5];
    float* out = (float*)d_out;

    char* w = (char*)d_ws;
    size_t off = 0;
    auto carve = [&](size_t bytes) -> void* {
        void* ptr = w + off;
        off += (bytes + 511) & ~(size_t)511;
        return ptr;
    };
    float2* P     = (float2*)carve((size_t)DHWn * 8);
    float2* R     = (float2*)carve((size_t)DHWn * 8);
    float2* Bv    = (float2*)carve((size_t)DHWn * 8);
    float2* COIL  = (float2*)carve((size_t)Cn * HWn * 8);
    float*  MASKP = (float*)carve((size_t)HWn * 4);
    float2* TWS   = (float2*)carve(TW_NT * 8);
    double* S     = (double*)carve(64 * 8);

    size_t imgSet = (size_t)DHWn * 8;   // one coil-slot (12 slices), 9.63 MB
    // (coils staged per chunk, z-splits of the combine); NZ divides cc.
    int cc = 1, NZ = 1;
    {
        const int cand[6][2] = {{10,2},{10,1},{5,1},{2,1},{1,1},{1,1}};
        for (int i = 0; i < 6; ++i) {
            size_t need = off + (size_t)(cand[i][0] + cand[i][1]) * imgSet;
            if (need <= ws_size) { cc = cand[i][0]; NZ = cand[i][1]; break; }
        }
    }
    float2* Qp  = (float2*)carve((size_t)NZ * imgSet);   // NZ partial-q buffers
    float2* Y1T = (float2*)carve((size_t)cc * imgSet);   // staged slices [c][d][oct][h][l8]
    int nch = Cn / cc;
    int ccz = cc / NZ;

    k_init_misc<<<1, 1024, 0, stream>>>(TWS, S);
    k_build_p<<<1024, 256, 0, stream>>>(z, zf, miu, P, R, Bv, S);
    k_build_coil<<<1024, 256, 0, stream>>>(coil_r, coil_i, COIL);
    k_build_mask<<<512, 256, 0, stream>>>(maskp, MASKP);

    for (int it = 0; it < 5; ++it) {
        for (int ch = 0; ch < nch; ++ch) {
            int cs = ch * cc;
            dim3 gf(Hn / 8, Dn, cc);    // 56 x 12 x cc
            dim3 gc(28, 24, cc);        // octet x (d + 12*half) x cc
            dim3 gi(Hn / 8, Dn, NZ);    // 56 x 12 x NZ, each z does cc/NZ coils
            k_rowfft0<<<gf, 256, 0, stream>>>(P, COIL, Y1T, TWS, cs);
            k_colfft<<<gc, 256, 0, stream>>>(Y1T, MASKP, TWS);
            k_irow_combine<<<gi, 256, 0, stream>>>(Y1T, COIL, P, Qp, miu, S, TWS,
                                                   ccz, cs, ch == 0 ? 1 : 0,
                                                   ch == nch - 1 ? 1 : 0, it);
        }
        k_update_br<<<1024, 256, 0, stream>>>(S, S, it, (const float4*)P, (const float4*)Qp,
                                              NZ, (float4*)Bv, (float4*)R);
        if (it < 4) k_update_p<<<1024, 256, 0, stream>>>(S, it, (const float4*)R, (float4*)P);
    }
    k_output<<<1024, 256, 0, stream>>>(Bv, out);
}